// Round 20
// baseline (274.872 us; speedup 1.0000x reference)
//
#include <hip/hip_runtime.h>
#include <math.h>

#define KNB 16
#define NPTS 4096
#define NB 2
#define CH 256
#define BNEPS 1e-5f

#define MTOT (NB * NPTS * KNB)   // 131072 rows of (b,n,k)
#define BM 128                   // GEMM M tile

typedef short bf16x8 __attribute__((ext_vector_type(8)));
typedef float f32x4 __attribute__((ext_vector_type(4)));

__device__ __forceinline__ unsigned short f2bf(float x) {
  unsigned u = __float_as_uint(x);
  return (unsigned short)((u + 0x7fffu + ((u >> 16) & 1u)) >> 16);
}
__device__ __forceinline__ float bf2f(unsigned short h) {
  return __uint_as_float(((unsigned)h) << 16);
}

#define GLOAD_LDS16(g, l)                                                     \
  __builtin_amdgcn_global_load_lds(                                           \
      (const __attribute__((address_space(1))) unsigned int*)(g),             \
      (__attribute__((address_space(3))) unsigned int*)(l), 16, 0, 0)

// ------- merged prep v2 (r18-validated): tiled feat transpose | conv_w | pack -------
__global__ __launch_bounds__(256) void prep_kernel(
    const float* __restrict__ pc1, const float* __restrict__ pc2,
    const float* __restrict__ f1, const float* __restrict__ f2,
    const float* __restrict__ W0, const float* __restrict__ W1,
    const float* __restrict__ W2,
    float4* __restrict__ pk1, float4* __restrict__ pk2,
    unsigned short* __restrict__ f1b, unsigned short* __restrict__ f2b,
    unsigned short* __restrict__ W0a, unsigned short* __restrict__ W0bp,
    unsigned short* __restrict__ W1b, unsigned short* __restrict__ W2b) {
  __shared__ float tile[64][65];
  int gid = blockIdx.x;
  int t = threadIdx.x;
  if (gid < 1024) {
    const float* in = (gid < 512) ? f1 : f2;
    unsigned short* out = (gid < 512) ? f1b : f2b;
    int rem = gid & 511;
    int b = rem >> 8;
    int c0 = ((rem >> 6) & 3) << 6;
    int n0 = (rem & 63) << 6;
    int cL = t >> 6;   // 0..3
    int nL = t & 63;
#pragma unroll
    for (int i = 0; i < 16; ++i) {
      int cl = i * 4 + cL;
      tile[cl][nL] = in[((size_t)(b * 256 + c0 + cl)) * 4096 + n0 + nL];
    }
    __syncthreads();
#pragma unroll
    for (int i = 0; i < 16; ++i) {
      int nl = i * 4 + cL;
      out[((size_t)(b * 4096 + n0 + nl)) * 256 + c0 + nL] = f2bf(tile[nL][nl]);
    }
  } else if (gid < 1792) {
    int r = gid - 1024, c = t;
    if (r < 256) {
      W0a[r * 256 + c] = f2bf(W0[(size_t)r * 515 + c]);
      W0bp[r * 256 + c] = f2bf(W0[(size_t)r * 515 + 256 + c]);
    } else if (r < 512) {
      int rr = r - 256;
      W1b[rr * 256 + c] = f2bf(W1[rr * 256 + c]);
    } else {
      int rr = r - 512;
      W2b[rr * 256 + c] = f2bf(W2[rr * 256 + c]);
    }
  } else {
    int id = (gid - 1792) * 256 + t;  // 0..16383
    const float* in = (id < 8192) ? pc1 : pc2;
    float4* out = (id < 8192) ? pk1 : pk2;
    int q = id & 8191;
    int b = q >> 12, n = q & 4095;
    const float* pb = in + (size_t)b * 3 * NPTS;
    float x = pb[n], y = pb[NPTS + n], z = pb[2 * NPTS + n];
    float nn = __fadd_rn(__fadd_rn(__fmul_rn(x, x), __fmul_rn(y, y)), __fmul_rn(z, z));
    out[q] = make_float4(x, y, z, nn);
  }
}

// ------- merged knn3c + small_gemm (r19-validated) -------
__global__ __launch_bounds__(512) void knn_sg_kernel(
    const float4* __restrict__ pk1, const float4* __restrict__ pk2,
    int* __restrict__ idx1, int* __restrict__ idx2,
    const unsigned short* __restrict__ f1b, const unsigned short* __restrict__ f2b,
    const unsigned short* __restrict__ W0a, const unsigned short* __restrict__ W0bp,
    const float* __restrict__ b0, float* __restrict__ g1, float* __restrict__ G2) {
  __shared__ __align__(16) char mem[73728];  // knn: 8*4096 u16 + 8*128 u64 ; gemm: 24KB
  if (blockIdx.x < 2048) {
    const int wid = threadIdx.x >> 6;        // 0..7
    const int lane = threadIdx.x & 63;
    const int gw = blockIdx.x * 8 + wid;     // 0..16383
    const int which = gw >> 13;
    const int qi = gw & 8191;
    const int b = qi >> 12;
    const float4* pts = (which ? pk1 : pk2) + ((size_t)b << 12);
    float4 qp = pk1[qi];
    const float qx = qp.x, qy = qp.y, qz = qp.z, qn = qp.w;
    unsigned short* S = (unsigned short*)mem + wid * 4096;

    unsigned int mymin = 0xFFFFu;
#pragma unroll 8
    for (int it = 0; it < 64; ++it) {
      int j = (it << 6) + lane;
      float4 pt = pts[j];
      float dot = __fadd_rn(__fadd_rn(__fmul_rn(qx, pt.x), __fmul_rn(qy, pt.y)),
                            __fmul_rn(qz, pt.z));
      float d = __fadd_rn(__fsub_rn(qn, __fmul_rn(2.f, dot)), pt.w);
      unsigned int u = __float_as_uint(d);
      unsigned int s = u ^ (unsigned int)(((int)u >> 31) | (int)0x80000000);
      unsigned int k16 = s >> 16;
      S[j] = (unsigned short)k16;
      mymin = mymin < k16 ? mymin : k16;
    }

    unsigned int v = mymin;
#pragma unroll
    for (int k = 2; k <= 64; k <<= 1) {
#pragma unroll
      for (int jj = k >> 1; jj >= 1; jj >>= 1) {
        unsigned int o = (unsigned int)__shfl_xor((int)v, jj);
        bool up = ((lane & k) == 0);
        bool low = ((lane & jj) == 0);
        bool tmin = (up == low);
        unsigned int mn = v < o ? v : o;
        unsigned int mx = v < o ? o : v;
        v = tmin ? mn : mx;
      }
    }

    unsigned long long* SV = (unsigned long long*)(mem + 65536) + wid * 128;
    unsigned int thr = (unsigned int)__shfl((int)v, 15);
    int base = 0;
    for (int attempt = 0; attempt < 2; ++attempt) {
      SV[lane] = ~0ull;
      SV[64 + lane] = ~0ull;
      base = 0;
      for (int it = 0; it < 64; ++it) {
        int j = (it << 6) + lane;
        bool hit = (unsigned int)S[j] <= thr;
        unsigned long long m = __ballot(hit);
        if (m) {
          float4 pt = pts[j];
          float dot = __fadd_rn(__fadd_rn(__fmul_rn(qx, pt.x), __fmul_rn(qy, pt.y)),
                                __fmul_rn(qz, pt.z));
          float d = __fadd_rn(__fsub_rn(qn, __fmul_rn(2.f, dot)), pt.w);
          unsigned int u = __float_as_uint(d);
          unsigned int s = u ^ (unsigned int)(((int)u >> 31) | (int)0x80000000);
          int r = base + (int)__popcll(m & ((1ull << lane) - 1ull));
          if (hit && r < 128) SV[r] = ((unsigned long long)s << 32) | (unsigned int)j;
          base += (int)__popcll(m);
        }
      }
      if (base <= 128) break;
      if (attempt == 0) {
        int idx = 23, cnt = 0, tries = 0;
        for (;;) {
          thr = (unsigned int)__shfl((int)v, idx);
          cnt = 0;
          for (int it = 0; it < 64; ++it) {
            unsigned long long m = __ballot((unsigned int)S[(it << 6) + lane] <= thr);
            cnt += __popcll(m);
          }
          if ((cnt >= 16 && cnt <= 128) || ++tries >= 6) break;
          if (cnt < 16) idx = (idx + 12 > 63) ? 63 : idx + 12;
          else idx = (idx - 8 < 0) ? 0 : idx - 8;
        }
      }
    }
    unsigned long long k0 = SV[lane];
    unsigned long long k1 = SV[64 + lane];

#pragma unroll
    for (int k = 2; k <= 128; k <<= 1) {
#pragma unroll
      for (int jj = k >> 1; jj >= 1; jj >>= 1) {
        if (jj == 64) {
          unsigned long long a = k0 < k1 ? k0 : k1;
          unsigned long long c = k0 < k1 ? k1 : k0;
          k0 = a; k1 = c;
        } else {
          {
            unsigned long long o = __shfl_xor(k0, jj);
            bool up = ((lane & k) == 0);
            bool low = ((lane & jj) == 0);
            bool tmin = (up == low);
            unsigned long long mn = k0 < o ? k0 : o;
            unsigned long long mx = k0 < o ? o : k0;
            k0 = tmin ? mn : mx;
          }
          {
            unsigned long long o = __shfl_xor(k1, jj);
            int e = 64 + lane;
            bool up = ((e & k) == 0);
            bool low = ((lane & jj) == 0);
            bool tmin = (up == low);
            unsigned long long mn = k1 < o ? k1 : o;
            unsigned long long mx = k1 < o ? o : k1;
            k1 = tmin ? mn : mx;
          }
        }
      }
    }

    int* op = (which ? idx2 : idx1) + (size_t)qi * KNB;
    if (lane < 16) op[lane] = (int)(k0 & 0xFFFFFFFFu);
  } else {
    // ---- small_gemm section (byte-identical body; smem = shared pool) ----
    char* smem = mem;
    const int tid = threadIdx.x;
    const int lane = tid & 63;
    const int w = tid >> 6;
    const int wm = w >> 2, wn = w & 3;
    const int bid = blockIdx.x - 2048;       // 0..127
    const bool isG2 = bid >= 64;
    const int m0 = (bid & 63) * BM;
    const unsigned short* Asrc = isG2 ? f2b : f1b;
    const unsigned short* Wb = isG2 ? W0bp : W0a;
    float* dst = isG2 ? G2 : g1;

    f32x4 acc[4][4];
#pragma unroll
    for (int nf = 0; nf < 4; ++nf) {
      float bv = isG2 ? 0.f : b0[wn * 64 + nf * 16 + (lane & 15)];
#pragma unroll
      for (int mf = 0; mf < 4; ++mf) acc[mf][nf] = (f32x4){bv, bv, bv, bv};
    }

    const int ar = tid >> 2;
    const int aql = (tid & 3) ^ ((ar >> 1) & 3);
    const int am = m0 + ar;
    const int br0 = tid >> 2;
    const int bq0 = (tid & 3) ^ ((br0 >> 1) & 3);
    const int br1 = (tid + 512) >> 2;
    const int bq1 = (tid & 3) ^ ((br1 >> 1) & 3);

    char* AsW = smem + (w << 10);
    char* BsW0 = smem + 8192 + (w << 10);
    char* BsW1 = smem + 8192 + 8192 + (w << 10);

    for (int kc = 0; kc < 8; ++kc) {
      __syncthreads();
      GLOAD_LDS16(Asrc + ((size_t)am << 8) + kc * 32 + aql * 8, AsW);
      GLOAD_LDS16(Wb + (size_t)br0 * 256 + kc * 32 + bq0 * 8, BsW0);
      GLOAD_LDS16(Wb + (size_t)br1 * 256 + kc * 32 + bq1 * 8, BsW1);
      __syncthreads();

      bf16x8 af[4], bfr[4];
#pragma unroll
      for (int mf = 0; mf < 4; ++mf) {
        int r = wm * 64 + mf * 16 + (lane & 15);
        int off = r * 64 + ((((lane >> 4)) ^ ((r >> 1) & 3)) << 4);
        af[mf] = *(const bf16x8*)(smem + off);
      }
#pragma unroll
      for (int nf = 0; nf < 4; ++nf) {
        int r = wn * 64 + nf * 16 + (lane & 15);
        int off = r * 64 + ((((lane >> 4)) ^ ((r >> 1) & 3)) << 4);
        bfr[nf] = *(const bf16x8*)(smem + 8192 + off);
      }
#pragma unroll
      for (int mf = 0; mf < 4; ++mf)
#pragma unroll
        for (int nf = 0; nf < 4; ++nf)
          acc[mf][nf] = __builtin_amdgcn_mfma_f32_16x16x32_bf16(af[mf], bfr[nf], acc[mf][nf], 0, 0, 0);
    }

#pragma unroll
    for (int mf = 0; mf < 4; ++mf) {
#pragma unroll
      for (int nf = 0; nf < 4; ++nf) {
        int n = wn * 64 + nf * 16 + (lane & 15);
#pragma unroll
        for (int j = 0; j < 4; ++j) {
          int m = m0 + wm * 64 + mf * 16 + (lane >> 4) * 4 + j;
          dst[(size_t)m * 256 + n] = acc[mf][nf][j];  // f32, no activation
        }
      }
    }
  }
}

// -------- combine: h1[m] = leaky(g1[bn] + G2[nbr] + dir.W0c); also weightnet1 hidden ------
__global__ __launch_bounds__(256) void combine_kernel(
    const float* __restrict__ g1, const float* __restrict__ G2,
    const float* __restrict__ W0,   // raw [256][515], cols 512..514 = W0c
    const float* __restrict__ pc1, const float* __restrict__ pc2,
    const int* __restrict__ idx1,
    const float* __restrict__ wW1, const float* __restrict__ wb1,
    const float* __restrict__ wg, const float* __restrict__ wbe,
    const float* __restrict__ wmn, const float* __restrict__ wv,
    unsigned short* __restrict__ h1, float* __restrict__ h1wn) {
  __shared__ int nbrs[KNB];
  __shared__ float dirs[KNB][4];
  int bn = blockIdx.x;
  int b = bn >> 12, n = bn & 4095;
  int t = threadIdx.x;
  if (t < KNB) nbrs[t] = idx1[(size_t)bn * KNB + t];
  __syncthreads();
  if (t < 128) {
    int k = t >> 3, jj = t & 7;
    int j = nbrs[k];
    const float* p1 = pc1 + (size_t)b * 3 * NPTS;
    const float* p2 = pc2 + (size_t)b * 3 * NPTS;
    float d0 = p2[j] - p1[n];
    float d1 = p2[NPTS + j] - p1[NPTS + n];
    float d2 = p2[2 * NPTS + j] - p1[2 * NPTS + n];
    if (jj == 0) { dirs[k][0] = d0; dirs[k][1] = d1; dirs[k][2] = d2; }
    float hv = wb1[jj];
    hv = fmaf(d0, wW1[jj * 3], hv);
    hv = fmaf(d1, wW1[jj * 3 + 1], hv);
    hv = fmaf(d2, wW1[jj * 3 + 2], hv);
    hv = wg[jj] * (hv - wmn[jj]) * (1.f / sqrtf(wv[jj] + BNEPS)) + wbe[jj];
    h1wn[(size_t)(bn * KNB + k) * 8 + jj] = fmaxf(hv, 0.f);
  }
  __syncthreads();
  int c = t;
  float g1v = g1[((size_t)bn << 8) + c];
  float wc0 = W0[(size_t)c * 515 + 512];
  float wc1 = W0[(size_t)c * 515 + 513];
  float wc2 = W0[(size_t)c * 515 + 514];
  const float* G2b = G2 + (((size_t)b << 12) << 8);
  unsigned short* hp = h1 + ((size_t)bn * KNB) * 256 + c;
#pragma unroll
  for (int k = 0; k < KNB; ++k) {
    float s = g1v + G2b[((size_t)nbrs[k] << 8) + c];
    s = fmaf(dirs[k][0], wc0, s);
    s = fmaf(dirs[k][1], wc1, s);
    s = fmaf(dirs[k][2], wc2, s);
    s = s >= 0.f ? s : 0.1f * s;
    hp[k * 256] = f2bf(s);
  }
}

// ---------------- gemm256 (r5-validated): [M x 256] @ [256 x 256] -> leaky -> bf16 --------
__global__ __launch_bounds__(512) void gemm256(
    const unsigned short* __restrict__ Asrc, const unsigned short* __restrict__ Wb,
    const float* __restrict__ bias, unsigned short* __restrict__ dst) {
  __shared__ char smem[8192 + 16384];
  const int tid = threadIdx.x;
  const int lane = tid & 63;
  const int w = tid >> 6;
  const int wm = w >> 2, wn = w & 3;
  const int m0 = blockIdx.x * BM;

  f32x4 acc[4][4];
#pragma unroll
  for (int nf = 0; nf < 4; ++nf) {
    float bv = bias[wn * 64 + nf * 16 + (lane & 15)];
#pragma unroll
    for (int mf = 0; mf < 4; ++mf) acc[mf][nf] = (f32x4){bv, bv, bv, bv};
  }

  const int ar = tid >> 2;
  const int aql = (tid & 3) ^ ((ar >> 1) & 3);
  const int am = m0 + ar;
  const int br0 = tid >> 2;
  const int bq0 = (tid & 3) ^ ((br0 >> 1) & 3);
  const int br1 = (tid + 512) >> 2;
  const int bq1 = (tid & 3) ^ ((br1 >> 1) & 3);

  char* AsW = smem + (w << 10);
  char* BsW0 = smem + 8192 + (w << 10);
  char* BsW1 = smem + 8192 + 8192 + (w << 10);

  for (int kc = 0; kc < 8; ++kc) {
    __syncthreads();
    GLOAD_LDS16(Asrc + ((size_t)am << 8) + kc * 32 + aql * 8, AsW);
    GLOAD_LDS16(Wb + (size_t)br0 * 256 + kc * 32 + bq0 * 8, BsW0);
    GLOAD_LDS16(Wb + (size_t)br1 * 256 + kc * 32 + bq1 * 8, BsW1);
    __syncthreads();

    bf16x8 af[4], bfr[4];
#pragma unroll
    for (int mf = 0; mf < 4; ++mf) {
      int r = wm * 64 + mf * 16 + (lane & 15);
      int off = r * 64 + ((((lane >> 4)) ^ ((r >> 1) & 3)) << 4);
      af[mf] = *(const bf16x8*)(smem + off);
    }
#pragma unroll
    for (int nf = 0; nf < 4; ++nf) {
      int r = wn * 64 + nf * 16 + (lane & 15);
      int off = r * 64 + ((((lane >> 4)) ^ ((r >> 1) & 3)) << 4);
      bfr[nf] = *(const bf16x8*)(smem + 8192 + off);
    }
#pragma unroll
    for (int mf = 0; mf < 4; ++mf)
#pragma unroll
      for (int nf = 0; nf < 4; ++nf)
        acc[mf][nf] = __builtin_amdgcn_mfma_f32_16x16x32_bf16(af[mf], bfr[nf], acc[mf][nf], 0, 0, 0);
  }

#pragma unroll
  for (int mf = 0; mf < 4; ++mf) {
#pragma unroll
    for (int nf = 0; nf < 4; ++nf) {
      int n = wn * 64 + nf * 16 + (lane & 15);
#pragma unroll
      for (int j = 0; j < 4; ++j) {
        int m = m0 + wm * 64 + mf * 16 + (lane >> 4) * 4 + j;
        float v = acc[mf][nf][j];
        v = v >= 0.f ? v : 0.1f * v;
        dst[(size_t)m * 256 + n] = f2bf(v);
      }
    }
  }
}

// ------- gemm256_wred: L2 GEMM + fused weightnet1 K-reduction -> out1 [8192][256] f32 -----
__global__ __launch_bounds__(512) void gemm256_wred(
    const unsigned short* __restrict__ Asrc, const unsigned short* __restrict__ Wb,
    const float* __restrict__ bias, const float* __restrict__ h1wn,
    const float* __restrict__ wW2, const float* __restrict__ wb2,
    float* __restrict__ out1) {
  __shared__ char smem[8192 + 16384];
  __shared__ float hw[1024];                 // 8 bn x 16 k x 8 jj
  const int tid = threadIdx.x;
  const int lane = tid & 63;
  const int w = tid >> 6;
  const int wm = w >> 2, wn = w & 3;
  const int m0 = blockIdx.x * BM;

  hw[tid] = h1wn[(size_t)blockIdx.x * 1024 + tid];
  hw[tid + 512] = h1wn[(size_t)blockIdx.x * 1024 + 512 + tid];

  f32x4 acc[4][4];
#pragma unroll
  for (int nf = 0; nf < 4; ++nf) {
    float bv = bias[wn * 64 + nf * 16 + (lane & 15)];
#pragma unroll
    for (int mf = 0; mf < 4; ++mf) acc[mf][nf] = (f32x4){bv, bv, bv, bv};
  }

  const int ar = tid >> 2;
  const int aql = (tid & 3) ^ ((ar >> 1) & 3);
  const int am = m0 + ar;
  const int br0 = tid >> 2;
  const int bq0 = (tid & 3) ^ ((br0 >> 1) & 3);
  const int br1 = (tid + 512) >> 2;
  const int bq1 = (tid & 3) ^ ((br1 >> 1) & 3);

  char* AsW = smem + (w << 10);
  char* BsW0 = smem + 8192 + (w << 10);
  char* BsW1 = smem + 8192 + 8192 + (w << 10);

  for (int kc = 0; kc < 8; ++kc) {
    __syncthreads();
    GLOAD_LDS16(Asrc + ((size_t)am << 8) + kc * 32 + aql * 8, AsW);
    GLOAD_LDS16(Wb + (size_t)br0 * 256 + kc * 32 + bq0 * 8, BsW0);
    GLOAD_LDS16(Wb + (size_t)br1 * 256 + kc * 32 + bq1 * 8, BsW1);
    __syncthreads();

    bf16x8 af[4], bfr[4];
#pragma unroll
    for (int mf = 0; mf < 4; ++mf) {
      int r = wm * 64 + mf * 16 + (lane & 15);
      int off = r * 64 + ((((lane >> 4)) ^ ((r >> 1) & 3)) << 4);
      af[mf] = *(const bf16x8*)(smem + off);
    }
#pragma unroll
    for (int nf = 0; nf < 4; ++nf) {
      int r = wn * 64 + nf * 16 + (lane & 15);
      int off = r * 64 + ((((lane >> 4)) ^ ((r >> 1) & 3)) << 4);
      bfr[nf] = *(const bf16x8*)(smem + 8192 + off);
    }
#pragma unroll
    for (int mf = 0; mf < 4; ++mf)
#pragma unroll
      for (int nf = 0; nf < 4; ++nf)
        acc[mf][nf] = __builtin_amdgcn_mfma_f32_16x16x32_bf16(af[mf], bfr[nf], acc[mf][nf], 0, 0, 0);
  }

#pragma unroll
  for (int nf = 0; nf < 4; ++nf) {
    int n = wn * 64 + nf * 16 + (lane & 15);
    float wbv = wb2[n];
    float wr[8];
#pragma unroll
    for (int jj = 0; jj < 8; ++jj) wr[jj] = wW2[n * 8 + jj];
#pragma unroll
    for (int mf = 0; mf < 4; ++mf) {
      int bnL = wm * 4 + mf;                 // local bn group 0..7
      float part = 0.f;
#pragma unroll
      for (int j = 0; j < 4; ++j) {
        int k = (lane >> 4) * 4 + j;
        const float4* hp = (const float4*)&hw[(bnL * 16 + k) * 8];
        float4 ha = hp[0], hb = hp[1];
        float w1 = wbv;
        w1 = fmaf(ha.x, wr[0], w1); w1 = fmaf(ha.y, wr[1], w1);
        w1 = fmaf(ha.z, wr[2], w1); w1 = fmaf(ha.w, wr[3], w1);
        w1 = fmaf(hb.x, wr[4], w1); w1 = fmaf(hb.y, wr[5], w1);
        w1 = fmaf(hb.z, wr[6], w1); w1 = fmaf(hb.w, wr[7], w1);
        float v = acc[mf][nf][j];
        v = v >= 0.f ? v : 0.1f * v;
        v = bf2f(f2bf(v));                   // replicate unfused bf16 round-trip
        part = fmaf(w1, v, part);
      }
      part += __shfl_xor(part, 16);
      part += __shfl_xor(part, 32);
      if (lane < 16)
        out1[(size_t)(blockIdx.x * 8 + bnL) * 256 + n] = part;
    }
  }
}

// ---- stage 2 v2: 16 queries per block; coalesced full-line output writes ----
// Phase1: stage 16x16 neighbor idx. Phase2: 16x16x8 weightnet hidden into LDS
// (per-item arithmetic identical to validated stage2). Phase3: thread c loops
// nl,k in the same order as before (identical FMA chains); each thread's 16
// stores are consecutive addresses -> full 64B lines, no partial-line writes.
__global__ __launch_bounds__(256) void stage2_kernel(
    const float* __restrict__ out1, const float* __restrict__ pc1,
    const int* __restrict__ idx2,
    const float* __restrict__ wn_W1, const float* __restrict__ wn_b1,
    const float* __restrict__ wn_g, const float* __restrict__ wn_be,
    const float* __restrict__ wn_m, const float* __restrict__ wn_v,
    const float* __restrict__ wn_W2, const float* __restrict__ wn_b2,
    float* __restrict__ outp) {
  __shared__ int nbrs[16 * KNB];
  __shared__ float h1[16][KNB][8];
  int bn0 = blockIdx.x * 16;
  int b = bn0 >> 12, n0 = bn0 & 4095;
  int t = threadIdx.x;
  nbrs[t] = idx2[(size_t)bn0 * KNB + t];
  __syncthreads();
  // phase 2: 2048 items = 16 n x 16 k x 8 jj over 256 threads x 8
  const float* p1 = pc1 + (size_t)b * 3 * NPTS;
#pragma unroll
  for (int p = 0; p < 8; ++p) {
    int idx = p * 256 + t;
    int nq = idx >> 7;
    int rem = idx & 127;
    int k = rem >> 3, jj = rem & 7;
    int n = n0 + nq;
    int j = nbrs[nq * KNB + k];
    float d0 = p1[j] - p1[n];
    float d1 = p1[NPTS + j] - p1[NPTS + n];
    float d2v = p1[2 * NPTS + j] - p1[2 * NPTS + n];
    float hv = d0 * wn_W1[jj * 3] + d1 * wn_W1[jj * 3 + 1] + d2v * wn_W1[jj * 3 + 2] + wn_b1[jj];
    hv = wn_g[jj] * (hv - wn_m[jj]) * (1.f / sqrtf(wn_v[jj] + BNEPS)) + wn_be[jj];
    h1[nq][k][jj] = fmaxf(hv, 0.f);
  }
  __syncthreads();
  float wrow[8];
#pragma unroll
  for (int jj = 0; jj < 8; ++jj) wrow[jj] = wn_W2[t * 8 + jj];
  float wb = wn_b2[t];
  float* orow = outp + ((size_t)(b * CH) + t) * NPTS + n0;
#pragma unroll
  for (int nl = 0; nl < 16; ++nl) {
    float outv = 0.f;
#pragma unroll
    for (int k = 0; k < KNB; ++k) {
      float w2 = wb;
#pragma unroll
      for (int jj = 0; jj < 8; ++jj) w2 = fmaf(h1[nl][k][jj], wrow[jj], w2);
      float v = out1[((size_t)(b * NPTS) + nbrs[nl * KNB + k]) * CH + t];
      outv = fmaf(w2, v, outv);
    }
    orow[nl] = outv;
  }
}

extern "C" void kernel_launch(void* const* d_in, const int* in_sizes, int n_in,
                              void* d_out, int out_size, void* d_ws, size_t ws_size,
                              hipStream_t stream) {
  const float* pc1 = (const float*)d_in[0];
  const float* pc2 = (const float*)d_in[1];
  const float* f1 = (const float*)d_in[2];
  const float* f2 = (const float*)d_in[3];
  const float* W0 = (const float*)d_in[4];
  const float* b0 = (const float*)d_in[5];
  const float* W1 = (const float*)d_in[6];
  const float* b1 = (const float*)d_in[7];
  const float* W2 = (const float*)d_in[8];
  const float* b2 = (const float*)d_in[9];
  const float* wn1_W1 = (const float*)d_in[10];
  const float* wn1_b1 = (const float*)d_in[11];
  const float* wn1_g = (const float*)d_in[12];
  const float* wn1_be = (const float*)d_in[13];
  const float* wn1_m = (const float*)d_in[14];
  const float* wn1_v = (const float*)d_in[15];
  const float* wn1_W2 = (const float*)d_in[16];
  const float* wn1_b2 = (const float*)d_in[17];
  const float* wn2_W1 = (const float*)d_in[18];
  const float* wn2_b1 = (const float*)d_in[19];
  const float* wn2_g = (const float*)d_in[20];
  const float* wn2_be = (const float*)d_in[21];
  const float* wn2_m = (const float*)d_in[22];
  const float* wn2_v = (const float*)d_in[23];
  const float* wn2_W2 = (const float*)d_in[24];
  const float* wn2_b2 = (const float*)d_in[25];

  unsigned short* f1b = (unsigned short*)d_ws;                       // 8192*256 bf16
  unsigned short* f2b = f1b + (size_t)NB * NPTS * CH;
  unsigned short* W0a = f2b + (size_t)NB * NPTS * CH;                // 256*256 bf16
  unsigned short* W0bp = W0a + (size_t)256 * 256;
  unsigned short* W1b = W0bp + (size_t)256 * 256;
  unsigned short* W2b = W1b + (size_t)256 * 256;
  unsigned short* h = W2b + (size_t)256 * 256;                       // 131072*256 bf16
  float* g1 = (float*)(h + (size_t)MTOT * 256);                      // 8192*256 f32
  float* G2 = g1 + (size_t)NB * NPTS * CH;                           // 8192*256 f32
  float* h1wn = G2 + (size_t)NB * NPTS * CH;                         // 131072*8 f32
  float* out1 = h1wn + (size_t)MTOT * 8;                             // 8192*256 f32
  int* idx1 = (int*)(out1 + (size_t)NB * NPTS * CH);
  int* idx2 = idx1 + (size_t)MTOT;
  float4* pk1 = (float4*)(idx2 + (size_t)MTOT);
  float4* pk2 = pk1 + (size_t)NB * NPTS;

  prep_kernel<<<1024 + 768 + 64, 256, 0, stream>>>(
      pc1, pc2, f1, f2, W0, W1, W2, pk1, pk2, f1b, f2b, W0a, W0bp, W1b, W2b);
  knn_sg_kernel<<<2048 + 128, 512, 0, stream>>>(
      pk1, pk2, idx1, idx2, f1b, f2b, W0a, W0bp, b0, g1, G2);
  combine_kernel<<<NB * NPTS, 256, 0, stream>>>(
      g1, G2, W0, pc1, pc2, idx1, wn1_W1, wn1_b1, wn1_g, wn1_be, wn1_m, wn1_v,
      h, h1wn);
  gemm256<<<MTOT / BM, 512, 0, stream>>>(h, W1b, b1, h);
  gemm256_wred<<<MTOT / BM, 512, 0, stream>>>(h, W2b, b2, h1wn, wn1_W2, wn1_b2, out1);
  stage2_kernel<<<NB * NPTS / 16, 256, 0, stream>>>(
      out1, pc1, idx2, wn2_W1, wn2_b1, wn2_g, wn2_be, wn2_m, wn2_v, wn2_W2, wn2_b2,
      (float*)d_out);
}

// Round 21
// 225.179 us; speedup vs baseline: 1.2207x; 1.2207x over previous
//
#include <hip/hip_runtime.h>
#include <math.h>

#define KNB 16
#define NPTS 4096
#define NB 2
#define CH 256
#define BNEPS 1e-5f

#define MTOT (NB * NPTS * KNB)   // 131072 rows of (b,n,k)
#define BM 128                   // GEMM M tile

typedef short bf16x8 __attribute__((ext_vector_type(8)));
typedef float f32x4 __attribute__((ext_vector_type(4)));

__device__ __forceinline__ unsigned short f2bf(float x) {
  unsigned u = __float_as_uint(x);
  return (unsigned short)((u + 0x7fffu + ((u >> 16) & 1u)) >> 16);
}
__device__ __forceinline__ float bf2f(unsigned short h) {
  return __uint_as_float(((unsigned)h) << 16);
}

#define GLOAD_LDS16(g, l)                                                     \
  __builtin_amdgcn_global_load_lds(                                           \
      (const __attribute__((address_space(1))) unsigned int*)(g),             \
      (__attribute__((address_space(3))) unsigned int*)(l), 16, 0, 0)

// ------- merged prep v2 (r18-validated): tiled feat transpose | conv_w | pack -------
__global__ __launch_bounds__(256) void prep_kernel(
    const float* __restrict__ pc1, const float* __restrict__ pc2,
    const float* __restrict__ f1, const float* __restrict__ f2,
    const float* __restrict__ W0, const float* __restrict__ W1,
    const float* __restrict__ W2,
    float4* __restrict__ pk1, float4* __restrict__ pk2,
    unsigned short* __restrict__ f1b, unsigned short* __restrict__ f2b,
    unsigned short* __restrict__ W0a, unsigned short* __restrict__ W0bp,
    unsigned short* __restrict__ W1b, unsigned short* __restrict__ W2b) {
  __shared__ float tile[64][65];
  int gid = blockIdx.x;
  int t = threadIdx.x;
  if (gid < 1024) {
    const float* in = (gid < 512) ? f1 : f2;
    unsigned short* out = (gid < 512) ? f1b : f2b;
    int rem = gid & 511;
    int b = rem >> 8;
    int c0 = ((rem >> 6) & 3) << 6;
    int n0 = (rem & 63) << 6;
    int cL = t >> 6;   // 0..3
    int nL = t & 63;
#pragma unroll
    for (int i = 0; i < 16; ++i) {
      int cl = i * 4 + cL;
      tile[cl][nL] = in[((size_t)(b * 256 + c0 + cl)) * 4096 + n0 + nL];
    }
    __syncthreads();
#pragma unroll
    for (int i = 0; i < 16; ++i) {
      int nl = i * 4 + cL;
      out[((size_t)(b * 4096 + n0 + nl)) * 256 + c0 + nL] = f2bf(tile[nL][nl]);
    }
  } else if (gid < 1792) {
    int r = gid - 1024, c = t;
    if (r < 256) {
      W0a[r * 256 + c] = f2bf(W0[(size_t)r * 515 + c]);
      W0bp[r * 256 + c] = f2bf(W0[(size_t)r * 515 + 256 + c]);
    } else if (r < 512) {
      int rr = r - 256;
      W1b[rr * 256 + c] = f2bf(W1[rr * 256 + c]);
    } else {
      int rr = r - 512;
      W2b[rr * 256 + c] = f2bf(W2[rr * 256 + c]);
    }
  } else {
    int id = (gid - 1792) * 256 + t;  // 0..16383
    const float* in = (id < 8192) ? pc1 : pc2;
    float4* out = (id < 8192) ? pk1 : pk2;
    int q = id & 8191;
    int b = q >> 12, n = q & 4095;
    const float* pb = in + (size_t)b * 3 * NPTS;
    float x = pb[n], y = pb[NPTS + n], z = pb[2 * NPTS + n];
    float nn = __fadd_rn(__fadd_rn(__fmul_rn(x, x), __fmul_rn(y, y)), __fmul_rn(z, z));
    out[q] = make_float4(x, y, z, nn);
  }
}

// ------- merged knn3c + small_gemm (r19-validated) -------
__global__ __launch_bounds__(512) void knn_sg_kernel(
    const float4* __restrict__ pk1, const float4* __restrict__ pk2,
    int* __restrict__ idx1, int* __restrict__ idx2,
    const unsigned short* __restrict__ f1b, const unsigned short* __restrict__ f2b,
    const unsigned short* __restrict__ W0a, const unsigned short* __restrict__ W0bp,
    const float* __restrict__ b0, float* __restrict__ g1, float* __restrict__ G2) {
  __shared__ __align__(16) char mem[73728];  // knn: 8*4096 u16 + 8*128 u64 ; gemm: 24KB
  if (blockIdx.x < 2048) {
    const int wid = threadIdx.x >> 6;        // 0..7
    const int lane = threadIdx.x & 63;
    const int gw = blockIdx.x * 8 + wid;     // 0..16383
    const int which = gw >> 13;
    const int qi = gw & 8191;
    const int b = qi >> 12;
    const float4* pts = (which ? pk1 : pk2) + ((size_t)b << 12);
    float4 qp = pk1[qi];
    const float qx = qp.x, qy = qp.y, qz = qp.z, qn = qp.w;
    unsigned short* S = (unsigned short*)mem + wid * 4096;

    unsigned int mymin = 0xFFFFu;
#pragma unroll 8
    for (int it = 0; it < 64; ++it) {
      int j = (it << 6) + lane;
      float4 pt = pts[j];
      float dot = __fadd_rn(__fadd_rn(__fmul_rn(qx, pt.x), __fmul_rn(qy, pt.y)),
                            __fmul_rn(qz, pt.z));
      float d = __fadd_rn(__fsub_rn(qn, __fmul_rn(2.f, dot)), pt.w);
      unsigned int u = __float_as_uint(d);
      unsigned int s = u ^ (unsigned int)(((int)u >> 31) | (int)0x80000000);
      unsigned int k16 = s >> 16;
      S[j] = (unsigned short)k16;
      mymin = mymin < k16 ? mymin : k16;
    }

    unsigned int v = mymin;
#pragma unroll
    for (int k = 2; k <= 64; k <<= 1) {
#pragma unroll
      for (int jj = k >> 1; jj >= 1; jj >>= 1) {
        unsigned int o = (unsigned int)__shfl_xor((int)v, jj);
        bool up = ((lane & k) == 0);
        bool low = ((lane & jj) == 0);
        bool tmin = (up == low);
        unsigned int mn = v < o ? v : o;
        unsigned int mx = v < o ? o : v;
        v = tmin ? mn : mx;
      }
    }

    unsigned long long* SV = (unsigned long long*)(mem + 65536) + wid * 128;
    unsigned int thr = (unsigned int)__shfl((int)v, 15);
    int base = 0;
    for (int attempt = 0; attempt < 2; ++attempt) {
      SV[lane] = ~0ull;
      SV[64 + lane] = ~0ull;
      base = 0;
      for (int it = 0; it < 64; ++it) {
        int j = (it << 6) + lane;
        bool hit = (unsigned int)S[j] <= thr;
        unsigned long long m = __ballot(hit);
        if (m) {
          float4 pt = pts[j];
          float dot = __fadd_rn(__fadd_rn(__fmul_rn(qx, pt.x), __fmul_rn(qy, pt.y)),
                                __fmul_rn(qz, pt.z));
          float d = __fadd_rn(__fsub_rn(qn, __fmul_rn(2.f, dot)), pt.w);
          unsigned int u = __float_as_uint(d);
          unsigned int s = u ^ (unsigned int)(((int)u >> 31) | (int)0x80000000);
          int r = base + (int)__popcll(m & ((1ull << lane) - 1ull));
          if (hit && r < 128) SV[r] = ((unsigned long long)s << 32) | (unsigned int)j;
          base += (int)__popcll(m);
        }
      }
      if (base <= 128) break;
      if (attempt == 0) {
        int idx = 23, cnt = 0, tries = 0;
        for (;;) {
          thr = (unsigned int)__shfl((int)v, idx);
          cnt = 0;
          for (int it = 0; it < 64; ++it) {
            unsigned long long m = __ballot((unsigned int)S[(it << 6) + lane] <= thr);
            cnt += __popcll(m);
          }
          if ((cnt >= 16 && cnt <= 128) || ++tries >= 6) break;
          if (cnt < 16) idx = (idx + 12 > 63) ? 63 : idx + 12;
          else idx = (idx - 8 < 0) ? 0 : idx - 8;
        }
      }
    }
    unsigned long long k0 = SV[lane];
    unsigned long long k1 = SV[64 + lane];

#pragma unroll
    for (int k = 2; k <= 128; k <<= 1) {
#pragma unroll
      for (int jj = k >> 1; jj >= 1; jj >>= 1) {
        if (jj == 64) {
          unsigned long long a = k0 < k1 ? k0 : k1;
          unsigned long long c = k0 < k1 ? k1 : k0;
          k0 = a; k1 = c;
        } else {
          {
            unsigned long long o = __shfl_xor(k0, jj);
            bool up = ((lane & k) == 0);
            bool low = ((lane & jj) == 0);
            bool tmin = (up == low);
            unsigned long long mn = k0 < o ? k0 : o;
            unsigned long long mx = k0 < o ? o : k0;
            k0 = tmin ? mn : mx;
          }
          {
            unsigned long long o = __shfl_xor(k1, jj);
            int e = 64 + lane;
            bool up = ((e & k) == 0);
            bool low = ((lane & jj) == 0);
            bool tmin = (up == low);
            unsigned long long mn = k1 < o ? k1 : o;
            unsigned long long mx = k1 < o ? o : k1;
            k1 = tmin ? mn : mx;
          }
        }
      }
    }

    int* op = (which ? idx2 : idx1) + (size_t)qi * KNB;
    if (lane < 16) op[lane] = (int)(k0 & 0xFFFFFFFFu);
  } else {
    // ---- small_gemm section (byte-identical body; smem = shared pool) ----
    char* smem = mem;
    const int tid = threadIdx.x;
    const int lane = tid & 63;
    const int w = tid >> 6;
    const int wm = w >> 2, wn = w & 3;
    const int bid = blockIdx.x - 2048;       // 0..127
    const bool isG2 = bid >= 64;
    const int m0 = (bid & 63) * BM;
    const unsigned short* Asrc = isG2 ? f2b : f1b;
    const unsigned short* Wb = isG2 ? W0bp : W0a;
    float* dst = isG2 ? G2 : g1;

    f32x4 acc[4][4];
#pragma unroll
    for (int nf = 0; nf < 4; ++nf) {
      float bv = isG2 ? 0.f : b0[wn * 64 + nf * 16 + (lane & 15)];
#pragma unroll
      for (int mf = 0; mf < 4; ++mf) acc[mf][nf] = (f32x4){bv, bv, bv, bv};
    }

    const int ar = tid >> 2;
    const int aql = (tid & 3) ^ ((ar >> 1) & 3);
    const int am = m0 + ar;
    const int br0 = tid >> 2;
    const int bq0 = (tid & 3) ^ ((br0 >> 1) & 3);
    const int br1 = (tid + 512) >> 2;
    const int bq1 = (tid & 3) ^ ((br1 >> 1) & 3);

    char* AsW = smem + (w << 10);
    char* BsW0 = smem + 8192 + (w << 10);
    char* BsW1 = smem + 8192 + 8192 + (w << 10);

    for (int kc = 0; kc < 8; ++kc) {
      __syncthreads();
      GLOAD_LDS16(Asrc + ((size_t)am << 8) + kc * 32 + aql * 8, AsW);
      GLOAD_LDS16(Wb + (size_t)br0 * 256 + kc * 32 + bq0 * 8, BsW0);
      GLOAD_LDS16(Wb + (size_t)br1 * 256 + kc * 32 + bq1 * 8, BsW1);
      __syncthreads();

      bf16x8 af[4], bfr[4];
#pragma unroll
      for (int mf = 0; mf < 4; ++mf) {
        int r = wm * 64 + mf * 16 + (lane & 15);
        int off = r * 64 + ((((lane >> 4)) ^ ((r >> 1) & 3)) << 4);
        af[mf] = *(const bf16x8*)(smem + off);
      }
#pragma unroll
      for (int nf = 0; nf < 4; ++nf) {
        int r = wn * 64 + nf * 16 + (lane & 15);
        int off = r * 64 + ((((lane >> 4)) ^ ((r >> 1) & 3)) << 4);
        bfr[nf] = *(const bf16x8*)(smem + 8192 + off);
      }
#pragma unroll
      for (int mf = 0; mf < 4; ++mf)
#pragma unroll
        for (int nf = 0; nf < 4; ++nf)
          acc[mf][nf] = __builtin_amdgcn_mfma_f32_16x16x32_bf16(af[mf], bfr[nf], acc[mf][nf], 0, 0, 0);
    }

#pragma unroll
    for (int mf = 0; mf < 4; ++mf) {
#pragma unroll
      for (int nf = 0; nf < 4; ++nf) {
        int n = wn * 64 + nf * 16 + (lane & 15);
#pragma unroll
        for (int j = 0; j < 4; ++j) {
          int m = m0 + wm * 64 + mf * 16 + (lane >> 4) * 4 + j;
          dst[(size_t)m * 256 + n] = acc[mf][nf][j];  // f32, no activation
        }
      }
    }
  }
}

// -------- combine: h1[m] = leaky(g1[bn] + G2[nbr] + dir.W0c); also weightnet1 hidden ------
__global__ __launch_bounds__(256) void combine_kernel(
    const float* __restrict__ g1, const float* __restrict__ G2,
    const float* __restrict__ W0,   // raw [256][515], cols 512..514 = W0c
    const float* __restrict__ pc1, const float* __restrict__ pc2,
    const int* __restrict__ idx1,
    const float* __restrict__ wW1, const float* __restrict__ wb1,
    const float* __restrict__ wg, const float* __restrict__ wbe,
    const float* __restrict__ wmn, const float* __restrict__ wv,
    unsigned short* __restrict__ h1, float* __restrict__ h1wn) {
  __shared__ int nbrs[KNB];
  __shared__ float dirs[KNB][4];
  int bn = blockIdx.x;
  int b = bn >> 12, n = bn & 4095;
  int t = threadIdx.x;
  if (t < KNB) nbrs[t] = idx1[(size_t)bn * KNB + t];
  __syncthreads();
  if (t < 128) {
    int k = t >> 3, jj = t & 7;
    int j = nbrs[k];
    const float* p1 = pc1 + (size_t)b * 3 * NPTS;
    const float* p2 = pc2 + (size_t)b * 3 * NPTS;
    float d0 = p2[j] - p1[n];
    float d1 = p2[NPTS + j] - p1[NPTS + n];
    float d2 = p2[2 * NPTS + j] - p1[2 * NPTS + n];
    if (jj == 0) { dirs[k][0] = d0; dirs[k][1] = d1; dirs[k][2] = d2; }
    float hv = wb1[jj];
    hv = fmaf(d0, wW1[jj * 3], hv);
    hv = fmaf(d1, wW1[jj * 3 + 1], hv);
    hv = fmaf(d2, wW1[jj * 3 + 2], hv);
    hv = wg[jj] * (hv - wmn[jj]) * (1.f / sqrtf(wv[jj] + BNEPS)) + wbe[jj];
    h1wn[(size_t)(bn * KNB + k) * 8 + jj] = fmaxf(hv, 0.f);
  }
  __syncthreads();
  int c = t;
  float g1v = g1[((size_t)bn << 8) + c];
  float wc0 = W0[(size_t)c * 515 + 512];
  float wc1 = W0[(size_t)c * 515 + 513];
  float wc2 = W0[(size_t)c * 515 + 514];
  const float* G2b = G2 + (((size_t)b << 12) << 8);
  unsigned short* hp = h1 + ((size_t)bn * KNB) * 256 + c;
#pragma unroll
  for (int k = 0; k < KNB; ++k) {
    float s = g1v + G2b[((size_t)nbrs[k] << 8) + c];
    s = fmaf(dirs[k][0], wc0, s);
    s = fmaf(dirs[k][1], wc1, s);
    s = fmaf(dirs[k][2], wc2, s);
    s = s >= 0.f ? s : 0.1f * s;
    hp[k * 256] = f2bf(s);
  }
}

// ---------------- gemm256 (r5-validated): [M x 256] @ [256 x 256] -> leaky -> bf16 --------
__global__ __launch_bounds__(512) void gemm256(
    const unsigned short* __restrict__ Asrc, const unsigned short* __restrict__ Wb,
    const float* __restrict__ bias, unsigned short* __restrict__ dst) {
  __shared__ char smem[8192 + 16384];
  const int tid = threadIdx.x;
  const int lane = tid & 63;
  const int w = tid >> 6;
  const int wm = w >> 2, wn = w & 3;
  const int m0 = blockIdx.x * BM;

  f32x4 acc[4][4];
#pragma unroll
  for (int nf = 0; nf < 4; ++nf) {
    float bv = bias[wn * 64 + nf * 16 + (lane & 15)];
#pragma unroll
    for (int mf = 0; mf < 4; ++mf) acc[mf][nf] = (f32x4){bv, bv, bv, bv};
  }

  const int ar = tid >> 2;
  const int aql = (tid & 3) ^ ((ar >> 1) & 3);
  const int am = m0 + ar;
  const int br0 = tid >> 2;
  const int bq0 = (tid & 3) ^ ((br0 >> 1) & 3);
  const int br1 = (tid + 512) >> 2;
  const int bq1 = (tid & 3) ^ ((br1 >> 1) & 3);

  char* AsW = smem + (w << 10);
  char* BsW0 = smem + 8192 + (w << 10);
  char* BsW1 = smem + 8192 + 8192 + (w << 10);

  for (int kc = 0; kc < 8; ++kc) {
    __syncthreads();
    GLOAD_LDS16(Asrc + ((size_t)am << 8) + kc * 32 + aql * 8, AsW);
    GLOAD_LDS16(Wb + (size_t)br0 * 256 + kc * 32 + bq0 * 8, BsW0);
    GLOAD_LDS16(Wb + (size_t)br1 * 256 + kc * 32 + bq1 * 8, BsW1);
    __syncthreads();

    bf16x8 af[4], bfr[4];
#pragma unroll
    for (int mf = 0; mf < 4; ++mf) {
      int r = wm * 64 + mf * 16 + (lane & 15);
      int off = r * 64 + ((((lane >> 4)) ^ ((r >> 1) & 3)) << 4);
      af[mf] = *(const bf16x8*)(smem + off);
    }
#pragma unroll
    for (int nf = 0; nf < 4; ++nf) {
      int r = wn * 64 + nf * 16 + (lane & 15);
      int off = r * 64 + ((((lane >> 4)) ^ ((r >> 1) & 3)) << 4);
      bfr[nf] = *(const bf16x8*)(smem + 8192 + off);
    }
#pragma unroll
    for (int mf = 0; mf < 4; ++mf)
#pragma unroll
      for (int nf = 0; nf < 4; ++nf)
        acc[mf][nf] = __builtin_amdgcn_mfma_f32_16x16x32_bf16(af[mf], bfr[nf], acc[mf][nf], 0, 0, 0);
  }

#pragma unroll
  for (int mf = 0; mf < 4; ++mf) {
#pragma unroll
    for (int nf = 0; nf < 4; ++nf) {
      int n = wn * 64 + nf * 16 + (lane & 15);
#pragma unroll
      for (int j = 0; j < 4; ++j) {
        int m = m0 + wm * 64 + mf * 16 + (lane >> 4) * 4 + j;
        float v = acc[mf][nf][j];
        v = v >= 0.f ? v : 0.1f * v;
        dst[(size_t)m * 256 + n] = f2bf(v);
      }
    }
  }
}

// ------- gemm256_wred: L2 GEMM + fused weightnet1 K-reduction -> out1 [8192][256] f32 -----
__global__ __launch_bounds__(512) void gemm256_wred(
    const unsigned short* __restrict__ Asrc, const unsigned short* __restrict__ Wb,
    const float* __restrict__ bias, const float* __restrict__ h1wn,
    const float* __restrict__ wW2, const float* __restrict__ wb2,
    float* __restrict__ out1) {
  __shared__ char smem[8192 + 16384];
  __shared__ float hw[1024];                 // 8 bn x 16 k x 8 jj
  const int tid = threadIdx.x;
  const int lane = tid & 63;
  const int w = tid >> 6;
  const int wm = w >> 2, wn = w & 3;
  const int m0 = blockIdx.x * BM;

  hw[tid] = h1wn[(size_t)blockIdx.x * 1024 + tid];
  hw[tid + 512] = h1wn[(size_t)blockIdx.x * 1024 + 512 + tid];

  f32x4 acc[4][4];
#pragma unroll
  for (int nf = 0; nf < 4; ++nf) {
    float bv = bias[wn * 64 + nf * 16 + (lane & 15)];
#pragma unroll
    for (int mf = 0; mf < 4; ++mf) acc[mf][nf] = (f32x4){bv, bv, bv, bv};
  }

  const int ar = tid >> 2;
  const int aql = (tid & 3) ^ ((ar >> 1) & 3);
  const int am = m0 + ar;
  const int br0 = tid >> 2;
  const int bq0 = (tid & 3) ^ ((br0 >> 1) & 3);
  const int br1 = (tid + 512) >> 2;
  const int bq1 = (tid & 3) ^ ((br1 >> 1) & 3);

  char* AsW = smem + (w << 10);
  char* BsW0 = smem + 8192 + (w << 10);
  char* BsW1 = smem + 8192 + 8192 + (w << 10);

  for (int kc = 0; kc < 8; ++kc) {
    __syncthreads();
    GLOAD_LDS16(Asrc + ((size_t)am << 8) + kc * 32 + aql * 8, AsW);
    GLOAD_LDS16(Wb + (size_t)br0 * 256 + kc * 32 + bq0 * 8, BsW0);
    GLOAD_LDS16(Wb + (size_t)br1 * 256 + kc * 32 + bq1 * 8, BsW1);
    __syncthreads();

    bf16x8 af[4], bfr[4];
#pragma unroll
    for (int mf = 0; mf < 4; ++mf) {
      int r = wm * 64 + mf * 16 + (lane & 15);
      int off = r * 64 + ((((lane >> 4)) ^ ((r >> 1) & 3)) << 4);
      af[mf] = *(const bf16x8*)(smem + off);
    }
#pragma unroll
    for (int nf = 0; nf < 4; ++nf) {
      int r = wn * 64 + nf * 16 + (lane & 15);
      int off = r * 64 + ((((lane >> 4)) ^ ((r >> 1) & 3)) << 4);
      bfr[nf] = *(const bf16x8*)(smem + 8192 + off);
    }
#pragma unroll
    for (int mf = 0; mf < 4; ++mf)
#pragma unroll
      for (int nf = 0; nf < 4; ++nf)
        acc[mf][nf] = __builtin_amdgcn_mfma_f32_16x16x32_bf16(af[mf], bfr[nf], acc[mf][nf], 0, 0, 0);
  }

#pragma unroll
  for (int nf = 0; nf < 4; ++nf) {
    int n = wn * 64 + nf * 16 + (lane & 15);
    float wbv = wb2[n];
    float wr[8];
#pragma unroll
    for (int jj = 0; jj < 8; ++jj) wr[jj] = wW2[n * 8 + jj];
#pragma unroll
    for (int mf = 0; mf < 4; ++mf) {
      int bnL = wm * 4 + mf;                 // local bn group 0..7
      float part = 0.f;
#pragma unroll
      for (int j = 0; j < 4; ++j) {
        int k = (lane >> 4) * 4 + j;
        const float4* hp = (const float4*)&hw[(bnL * 16 + k) * 8];
        float4 ha = hp[0], hb = hp[1];
        float w1 = wbv;
        w1 = fmaf(ha.x, wr[0], w1); w1 = fmaf(ha.y, wr[1], w1);
        w1 = fmaf(ha.z, wr[2], w1); w1 = fmaf(ha.w, wr[3], w1);
        w1 = fmaf(hb.x, wr[4], w1); w1 = fmaf(hb.y, wr[5], w1);
        w1 = fmaf(hb.z, wr[6], w1); w1 = fmaf(hb.w, wr[7], w1);
        float v = acc[mf][nf][j];
        v = v >= 0.f ? v : 0.1f * v;
        v = bf2f(f2bf(v));                   // replicate unfused bf16 round-trip
        part = fmaf(w1, v, part);
      }
      part += __shfl_xor(part, 16);
      part += __shfl_xor(part, 32);
      if (lane < 16)
        out1[(size_t)(blockIdx.x * 8 + bnL) * 256 + n] = part;
    }
  }
}

// ---------------- stage 2 (r19-validated): gather out1, weightnet2, K-reduce --------------
__global__ __launch_bounds__(256) void stage2_kernel(
    const float* __restrict__ out1, const float* __restrict__ pc1,
    const int* __restrict__ idx2,
    const float* __restrict__ wn_W1, const float* __restrict__ wn_b1,
    const float* __restrict__ wn_g, const float* __restrict__ wn_be,
    const float* __restrict__ wn_m, const float* __restrict__ wn_v,
    const float* __restrict__ wn_W2, const float* __restrict__ wn_b2,
    float* __restrict__ outp) {
  __shared__ float h1[KNB][8];
  __shared__ int nbrs[KNB];
  int bn = blockIdx.x;
  int b = bn >> 12, n = bn & 4095;
  int t = threadIdx.x;
  if (t < KNB) nbrs[t] = idx2[(size_t)bn * KNB + t];
  __syncthreads();
  if (t < 128) {
    int k = t >> 3, jj = t & 7;
    int j = nbrs[k];
    const float* p1 = pc1 + (size_t)b * 3 * NPTS;
    float d0 = p1[j] - p1[n];
    float d1 = p1[NPTS + j] - p1[NPTS + n];
    float d2v = p1[2 * NPTS + j] - p1[2 * NPTS + n];
    float hv = d0 * wn_W1[jj * 3] + d1 * wn_W1[jj * 3 + 1] + d2v * wn_W1[jj * 3 + 2] + wn_b1[jj];
    hv = wn_g[jj] * (hv - wn_m[jj]) * (1.f / sqrtf(wn_v[jj] + BNEPS)) + wn_be[jj];
    h1[k][jj] = fmaxf(hv, 0.f);
  }
  __syncthreads();
  float wrow[8];
#pragma unroll
  for (int jj = 0; jj < 8; ++jj) wrow[jj] = wn_W2[t * 8 + jj];
  float wb = wn_b2[t];
  float outv = 0.f;
#pragma unroll
  for (int k = 0; k < KNB; ++k) {
    float w2 = wb;
#pragma unroll
    for (int jj = 0; jj < 8; ++jj) w2 = fmaf(h1[k][jj], wrow[jj], w2);
    float v = out1[((size_t)(b * NPTS) + nbrs[k]) * CH + t];
    outv = fmaf(w2, v, outv);
  }
  outp[((size_t)(b * CH) + t) * NPTS + n] = outv;
}

extern "C" void kernel_launch(void* const* d_in, const int* in_sizes, int n_in,
                              void* d_out, int out_size, void* d_ws, size_t ws_size,
                              hipStream_t stream) {
  const float* pc1 = (const float*)d_in[0];
  const float* pc2 = (const float*)d_in[1];
  const float* f1 = (const float*)d_in[2];
  const float* f2 = (const float*)d_in[3];
  const float* W0 = (const float*)d_in[4];
  const float* b0 = (const float*)d_in[5];
  const float* W1 = (const float*)d_in[6];
  const float* b1 = (const float*)d_in[7];
  const float* W2 = (const float*)d_in[8];
  const float* b2 = (const float*)d_in[9];
  const float* wn1_W1 = (const float*)d_in[10];
  const float* wn1_b1 = (const float*)d_in[11];
  const float* wn1_g = (const float*)d_in[12];
  const float* wn1_be = (const float*)d_in[13];
  const float* wn1_m = (const float*)d_in[14];
  const float* wn1_v = (const float*)d_in[15];
  const float* wn1_W2 = (const float*)d_in[16];
  const float* wn1_b2 = (const float*)d_in[17];
  const float* wn2_W1 = (const float*)d_in[18];
  const float* wn2_b1 = (const float*)d_in[19];
  const float* wn2_g = (const float*)d_in[20];
  const float* wn2_be = (const float*)d_in[21];
  const float* wn2_m = (const float*)d_in[22];
  const float* wn2_v = (const float*)d_in[23];
  const float* wn2_W2 = (const float*)d_in[24];
  const float* wn2_b2 = (const float*)d_in[25];

  unsigned short* f1b = (unsigned short*)d_ws;                       // 8192*256 bf16
  unsigned short* f2b = f1b + (size_t)NB * NPTS * CH;
  unsigned short* W0a = f2b + (size_t)NB * NPTS * CH;                // 256*256 bf16
  unsigned short* W0bp = W0a + (size_t)256 * 256;
  unsigned short* W1b = W0bp + (size_t)256 * 256;
  unsigned short* W2b = W1b + (size_t)256 * 256;
  unsigned short* h = W2b + (size_t)256 * 256;                       // 131072*256 bf16
  float* g1 = (float*)(h + (size_t)MTOT * 256);                      // 8192*256 f32
  float* G2 = g1 + (size_t)NB * NPTS * CH;                           // 8192*256 f32
  float* h1wn = G2 + (size_t)NB * NPTS * CH;                         // 131072*8 f32
  float* out1 = h1wn + (size_t)MTOT * 8;                             // 8192*256 f32
  int* idx1 = (int*)(out1 + (size_t)NB * NPTS * CH);
  int* idx2 = idx1 + (size_t)MTOT;
  float4* pk1 = (float4*)(idx2 + (size_t)MTOT);
  float4* pk2 = pk1 + (size_t)NB * NPTS;

  prep_kernel<<<1024 + 768 + 64, 256, 0, stream>>>(
      pc1, pc2, f1, f2, W0, W1, W2, pk1, pk2, f1b, f2b, W0a, W0bp, W1b, W2b);
  knn_sg_kernel<<<2048 + 128, 512, 0, stream>>>(
      pk1, pk2, idx1, idx2, f1b, f2b, W0a, W0bp, b0, g1, G2);
  combine_kernel<<<NB * NPTS, 256, 0, stream>>>(
      g1, G2, W0, pc1, pc2, idx1, wn1_W1, wn1_b1, wn1_g, wn1_be, wn1_m, wn1_v,
      h, h1wn);
  gemm256<<<MTOT / BM, 512, 0, stream>>>(h, W1b, b1, h);
  gemm256_wred<<<MTOT / BM, 512, 0, stream>>>(h, W2b, b2, h1wn, wn1_W2, wn1_b2, out1);
  stage2_kernel<<<NB * NPTS, 256, 0, stream>>>(
      out1, pc1, idx2, wn2_W1, wn2_b1, wn2_g, wn2_be, wn2_m, wn2_v, wn2_W2, wn2_b2,
      (float*)d_out);
}